// Round 15
// baseline (241.455 us; speedup 1.0000x reference)
//
#include <hip/hip_runtime.h>
#include <hip/hip_bf16.h>
#include <math.h>

typedef __attribute__((ext_vector_type(8))) short short8;
typedef __attribute__((ext_vector_type(4))) float floatx4;
typedef __attribute__((ext_vector_type(2))) float floatx2;
typedef __attribute__((ext_vector_type(4))) unsigned short ushortx4;

__device__ __forceinline__ float bf2f(unsigned short u) {
    union { unsigned int i; float f; } c; c.i = ((unsigned int)u) << 16; return c.f;
}
__device__ __forceinline__ unsigned short f2bf(float f) {
    union { float f; unsigned int i; } c; c.f = f;
    unsigned int x = c.i;
    return (unsigned short)((x + 0x7FFFu + ((x >> 16) & 1u)) >> 16);
}

// ---------- fp8 e4m3fn (OCP) encode/decode ----------
__device__ __forceinline__ unsigned char f2fp8(float f) {
    unsigned int u = __float_as_uint(f);
    unsigned int sign = (u >> 24) & 0x80u;
    unsigned int a = u & 0x7FFFFFFFu;
    if (a >= 0x43E00000u) return (unsigned char)(sign | 0x7Eu);  // saturate at 448
    if (a < 0x3C800000u) {  // below smallest normal 2^-6: denormal units of 2^-9
        int unit = (int)rintf(__uint_as_float(a) * 512.0f);
        return (unsigned char)(sign | (unsigned int)unit);
    }
    unsigned int r = a + 0x7FFFFu + ((a >> 20) & 1u);  // RNE at bit 20
    unsigned int e = (r >> 23) - 120u;
    unsigned int m = (r >> 20) & 7u;
    return (unsigned char)(sign | (e << 3) | m);
}

__device__ __forceinline__ float fp8dec1(unsigned int b) {
    unsigned int s = (b & 0x80u) << 24;
    unsigned int mag = (b & 0x7Fu) << 20;
    return __uint_as_float(s | mag) * __uint_as_float(0x7B800000u);  // * 2^120
}

template <bool W>
__device__ __forceinline__ floatx2 fp8pk2f(unsigned int v) {
#if defined(__has_builtin) && __has_builtin(__builtin_amdgcn_cvt_pk_f32_fp8)
    return __builtin_amdgcn_cvt_pk_f32_fp8(v, W);
#else
    floatx2 r;
    r[0] = fp8dec1((v >> (W ? 16 : 0)) & 0xFFu);
    r[1] = fp8dec1((v >> (W ? 24 : 8)) & 0xFFu);
    return r;
#endif
}

// decode 8 fp8 (as uint2) -> bf16x8 MFMA A-fragment (exact: e4m3 subset of bf16)
__device__ __forceinline__ short8 fp8x8_to_bf16x8(uint2 q) {
    floatx2 p0 = fp8pk2f<false>(q.x), p1 = fp8pk2f<true>(q.x);
    floatx2 p2 = fp8pk2f<false>(q.y), p3 = fp8pk2f<true>(q.y);
    short8 a;
    a[0] = (short)f2bf(p0[0]); a[1] = (short)f2bf(p0[1]);
    a[2] = (short)f2bf(p1[0]); a[3] = (short)f2bf(p1[1]);
    a[4] = (short)f2bf(p2[0]); a[5] = (short)f2bf(p2[1]);
    a[6] = (short)f2bf(p3[0]); a[7] = (short)f2bf(p3[1]);
    return a;
}

// pack 16 bf16 (two short8) -> 16 fp8 bytes as uint4
__device__ __forceinline__ uint4 pack16_fp8(short8 v0, short8 v1) {
    unsigned int w[4];
#pragma unroll
    for (int q = 0; q < 2; q++) {
        w[q] = (unsigned int)f2fp8(bf2f((unsigned short)v0[q * 4 + 0])) |
               ((unsigned int)f2fp8(bf2f((unsigned short)v0[q * 4 + 1])) << 8) |
               ((unsigned int)f2fp8(bf2f((unsigned short)v0[q * 4 + 2])) << 16) |
               ((unsigned int)f2fp8(bf2f((unsigned short)v0[q * 4 + 3])) << 24);
        w[q + 2] = (unsigned int)f2fp8(bf2f((unsigned short)v1[q * 4 + 0])) |
                   ((unsigned int)f2fp8(bf2f((unsigned short)v1[q * 4 + 1])) << 8) |
                   ((unsigned int)f2fp8(bf2f((unsigned short)v1[q * 4 + 2])) << 16) |
                   ((unsigned int)f2fp8(bf2f((unsigned short)v1[q * 4 + 3])) << 24);
    }
    uint4 u;
    u.x = w[0]; u.y = w[1]; u.z = w[2]; u.w = w[3];
    return u;
}

// ================= bucketed CSR build =================
constexpr int NB = 512;
constexpr int B1 = 256;

__global__ __launch_bounds__(256) void k_bhist(const int* dst, int E, int* cnt) {
    __shared__ int h[NB];
    int t = threadIdx.x, b = blockIdx.x;
    h[t] = 0; h[t + 256] = 0;
    __syncthreads();
    int chunk = (E + B1 - 1) / B1;
    int lo = b * chunk, hi = min(E, lo + chunk);
    for (int e = lo + t; e < hi; e += 256) atomicAdd(&h[dst[e] >> 8], 1);
    __syncthreads();
    cnt[(size_t)t * B1 + b] = h[t];
    cnt[(size_t)(t + 256) * B1 + b] = h[t + 256];
}

constexpr int SCAN_T = 256;
constexpr int SCAN_V = 8;
constexpr int SCAN_CHUNK = SCAN_T * SCAN_V;

__global__ void k_scan_part(const int* in, int* bsum, int N) {
    int b = blockIdx.x, t = threadIdx.x;
    int base = b * SCAN_CHUNK + t * SCAN_V;
    int s = 0;
#pragma unroll
    for (int j = 0; j < SCAN_V; j++) {
        int i = base + j;
        if (i < N) s += in[i];
    }
    __shared__ int wsums[SCAN_T / 64];
    for (int off = 32; off; off >>= 1) s += __shfl_down(s, off, 64);
    if ((t & 63) == 0) wsums[t >> 6] = s;
    __syncthreads();
    if (t == 0) {
        int tot = 0;
#pragma unroll
        for (int w = 0; w < SCAN_T / 64; w++) tot += wsums[w];
        bsum[b] = tot;
    }
}

__global__ void k_scan_top(int* bsum, int nb) {
    if (threadIdx.x == 0) {
        int run = 0;
        for (int i = 0; i < nb; i++) {
            int v = bsum[i];
            bsum[i] = run;
            run += v;
        }
    }
}

__global__ void k_scan_apply(const int* in, const int* bsum, int* out, int N) {
    int b = blockIdx.x, t = threadIdx.x;
    int base = b * SCAN_CHUNK + t * SCAN_V;
    int v[SCAN_V];
    int s = 0;
#pragma unroll
    for (int j = 0; j < SCAN_V; j++) {
        int i = base + j;
        v[j] = (i < N) ? in[i] : 0;
        s += v[j];
    }
    __shared__ int sums[SCAN_T];
    sums[t] = s;
    __syncthreads();
    for (int off = 1; off < SCAN_T; off <<= 1) {
        int x = (t >= off) ? sums[t - off] : 0;
        __syncthreads();
        sums[t] += x;
        __syncthreads();
    }
    int pre = bsum[b] + ((t == 0) ? 0 : sums[t - 1]);
#pragma unroll
    for (int j = 0; j < SCAN_V; j++) {
        int i = base + j;
        if (i < N) {
            out[i] = pre;
            pre += v[j];
            if (i == N - 1) out[N] = pre;
        }
    }
}

__global__ __launch_bounds__(256) void k_bscatter(const int* src, const int* dst, int E,
                                                  const int* cntoff, unsigned int* ebuf) {
    __shared__ int base[NB];
    __shared__ int lcur[NB];
    int t = threadIdx.x, b = blockIdx.x;
    for (int i = t; i < NB; i += 256) {
        base[i] = cntoff[(size_t)i * B1 + b];
        lcur[i] = 0;
    }
    __syncthreads();
    int chunk = (E + B1 - 1) / B1;
    int lo = b * chunk, hi = min(E, lo + chunk);
    for (int e = lo + t; e < hi; e += 256) {
        int d = dst[e];
        int cb = d >> 8;
        int slot = atomicAdd(&lcur[cb], 1);
        ebuf[base[cb] + slot] = (unsigned int)src[e] | ((unsigned int)(d & 255) << 17);
    }
}

__global__ __launch_bounds__(256) void k_build(const unsigned int* ebuf, const int* cntoff,
                                               int* rowptr, int* adj, int N, int E) {
    __shared__ int ldeg[256];
    __shared__ int lptr[256];
    __shared__ int lcur[256];
    __shared__ int tsum[256];
    int t = threadIdx.x, cb = blockIdx.x;
    int bbase = cntoff[(size_t)cb * B1];
    int bend = cntoff[(size_t)(cb + 1) * B1];
    ldeg[t] = 0;
    lcur[t] = 0;
    __syncthreads();
    for (int e = bbase + t; e < bend; e += 256) atomicAdd(&ldeg[ebuf[e] >> 17], 1);
    __syncthreads();
    tsum[t] = ldeg[t];
    __syncthreads();
    for (int off = 1; off < 256; off <<= 1) {
        int v = (t >= off) ? tsum[t - off] : 0;
        __syncthreads();
        tsum[t] += v;
        __syncthreads();
    }
    lptr[t] = tsum[t] - ldeg[t];
    __syncthreads();
    int node = cb * 256 + t;
    if (node < N) rowptr[node] = bbase + lptr[t];
    if (cb == 0 && t == 0) rowptr[N] = E;
    for (int e = bbase + t; e < bend; e += 256) {
        unsigned int pk = ebuf[e];
        int dl = pk >> 17;
        int ls = atomicAdd(&lcur[dl], 1);
        adj[bbase + lptr[dl] + ls] = (int)(pk & 0x1FFFF);
    }
}

// ---------------- combined prep: x->fp8 conversion AND 3x weight prep ----------------
__device__ __forceinline__ void prep_w_body(const float* Wl, const float* Wr,
                                            unsigned short* wf, int NOC, int t) {
    int total = 8 * NOC * 64 * 8;
    if (t >= total) return;
    int j = t & 7;
    int lane = (t >> 3) & 63;
    int rest = t >> 9;
    int oc = rest % NOC;
    int ks = rest / NOC;
    int k = ks * 32 + ((lane >> 4) << 3) + j;
    int o = oc * 16 + (lane & 15);
    float v = (k < 128) ? Wl[o * 128 + k] : Wr[o * 128 + (k - 128)];
    wf[t] = f2bf(v);
}

__device__ __forceinline__ void prep_w2_body(const float* Wl, const float* Wr,
                                             unsigned short* wf, int t) {
    int total = 4 * 8 * 64 * 8;
    if (t >= total) return;
    int j = t & 7;
    int lane = (t >> 3) & 63;
    int rest = t >> 9;
    int oc = rest % 8;
    int ks = rest / 8;
    int k = ks * 32 + ((lane >> 4) << 3) + j;
    int o16 = lane & 15;
    float v = (oc < 4) ? Wl[(oc * 16 + o16) * 128 + k] : Wr[((oc - 4) * 16 + o16) * 128 + k];
    wf[t] = f2bf(v);
}

__global__ __launch_bounds__(256) void k_prep(const float* x, unsigned char* xq, int n4,
                                              const float* Wl0, const float* Wr0, unsigned short* w0,
                                              const float* Wl1, const float* Wr1, unsigned short* w1,
                                              const float* Wl2, const float* Wr2, unsigned short* w2,
                                              int cvtBlocks) {
    int b = blockIdx.x;
    if (b < cvtBlocks) {
        int i = b * 256 + threadIdx.x;
        int idx = i * 4;
        if (idx < n4 * 4) {
            float4 v = *(const float4*)(x + idx);
            unsigned int qw = (unsigned int)f2fp8(v.x) | ((unsigned int)f2fp8(v.y) << 8) |
                              ((unsigned int)f2fp8(v.z) << 16) | ((unsigned int)f2fp8(v.w) << 24);
            *(unsigned int*)(xq + idx) = qw;
        }
    } else if (b < cvtBlocks + 128) {
        prep_w_body(Wl0, Wr0, w0, 8, (b - cvtBlocks) * 256 + threadIdx.x);
    } else if (b < cvtBlocks + 256) {
        prep_w_body(Wl1, Wr1, w1, 8, (b - cvtBlocks - 128) * 256 + threadIdx.x);
    } else {
        prep_w2_body(Wl2, Wr2, w2, (b - cvtBlocks - 256) * 256 + threadIdx.x);
    }
}

// ---------------- fp8 mean aggregation -> fp8 mean (32-lane group per node) ----------------
__global__ __launch_bounds__(256) void k_aggr8(const unsigned char* feat, const int* rowptr,
                                               const int* adj, unsigned char* aggr, int N) {
    int g = (blockIdx.x * blockDim.x + threadIdx.x) >> 5;
    int lane = threadIdx.x & 31;
    if (g >= N) return;
    int lo = rowptr[g], hi = rowptr[g + 1];
    float a0 = 0.f, a1 = 0.f, a2 = 0.f, a3 = 0.f;
    const unsigned char* fb = feat + lane * 4;
    int j = lo;
    for (; j + 8 <= hi; j += 8) {
        unsigned int v[8];
#pragma unroll
        for (int u = 0; u < 8; u++) {
            int s = adj[j + u];
            v[u] = *(const unsigned int*)(fb + (size_t)s * 128);
        }
#pragma unroll
        for (int u = 0; u < 8; u++) {
            floatx2 l2 = fp8pk2f<false>(v[u]);
            floatx2 h2 = fp8pk2f<true>(v[u]);
            a0 += l2[0]; a1 += l2[1]; a2 += h2[0]; a3 += h2[1];
        }
    }
    if (j < hi) {  // masked tail chunk: loads issued back-to-back
        unsigned int v[8];
        float w[8];
#pragma unroll
        for (int u = 0; u < 8; u++) {
            int jj = j + u;
            int s = adj[jj < hi ? jj : hi - 1];
            v[u] = *(const unsigned int*)(fb + (size_t)s * 128);
            w[u] = (jj < hi) ? 1.0f : 0.0f;
        }
#pragma unroll
        for (int u = 0; u < 8; u++) {
            floatx2 l2 = fp8pk2f<false>(v[u]);
            floatx2 h2 = fp8pk2f<true>(v[u]);
            a0 = fmaf(w[u], l2[0], a0);
            a1 = fmaf(w[u], l2[1], a1);
            a2 = fmaf(w[u], h2[0], a2);
            a3 = fmaf(w[u], h2[1], a3);
        }
    }
    float inv = 1.0f / (float)max(hi - lo, 1);
    unsigned int qw = (unsigned int)f2fp8(a0 * inv) | ((unsigned int)f2fp8(a1 * inv) << 8) |
                      ((unsigned int)f2fp8(a2 * inv) << 16) | ((unsigned int)f2fp8(a3 * inv) << 24);
    *(unsigned int*)(aggr + (size_t)g * 128 + lane * 4) = qw;
}

// ---------------- fused transform with LDS-staged weights ----------------
// h = relu([aggr|feat] @ W + b).  Weights (64 KB) staged global->LDS once per block;
// the output-staging buffer aliases the weight LDS after the last weight read.
// STAGE2=false: write fp8(h) -> outq.
// STAGE2=true: keep h in LDS; stage wf2 (32 KB) into freed LDS; layer-2:
//   t2 = h @ Wl2^T (fp8 -> t2q), self = h @ Wr2^T + bl2 (f32 -> outf).
template <bool STAGE2>
__global__ __launch_bounds__(256) void k_xform(const unsigned char* aggr,
                                               const unsigned char* featq,
                                               const unsigned short* w2f,
                                               const float* bias, unsigned char* outq,
                                               const unsigned short* wf2, const float* bias2,
                                               unsigned char* t2q, float* outf, int N) {
    __shared__ unsigned short wl[32768];  // 64 KB: stage-1 weights; later aliased
    const int t = threadIdx.x;
    const int wave = t >> 6;
    const int lane = t & 63;
    const int rloc = wave * 16 + (lane & 15);
    const int bRow0 = blockIdx.x * 64;
    const int row = bRow0 + rloc;
    const int kq = lane >> 4;

    // ---- stage 1 weights: 64 KB global -> LDS (16 x uint4 per thread) ----
    {
        const uint4* srcw = (const uint4*)w2f;
        uint4* dstw = (uint4*)wl;
#pragma unroll
        for (int i = 0; i < 16; i++) dstw[t + i * 256] = srcw[t + i * 256];
    }
    __syncthreads();

    floatx4 acc[8];
#pragma unroll
    for (int i = 0; i < 8; i++) acc[i] = (floatx4)0.0f;
    const bool rowOK = row < N;
    const unsigned char* arow = aggr + (size_t)row * 128;
    const unsigned char* frow = featq + (size_t)row * 128;
#pragma unroll
    for (int ks = 0; ks < 8; ks++) {
        short8 a;
        if (!rowOK) {
            a = (short8)0;
        } else {
            const unsigned char* p =
                (ks < 4) ? (arow + ks * 32 + kq * 8) : (frow + (ks - 4) * 32 + kq * 8);
            a = fp8x8_to_bf16x8(*(const uint2*)p);
        }
#pragma unroll
        for (int oc = 0; oc < 8; oc++) {
            short8 b = *(const short8*)&wl[((ks * 8 + oc) * 64 + lane) * 8];
            acc[oc] = __builtin_amdgcn_mfma_f32_16x16x32_bf16(a, b, acc[oc], 0, 0, 0);
        }
    }
    __syncthreads();  // all stage-1 weight reads done; LDS reusable

    // st aliases: !STAGE2 -> lds+0 ; STAGE2 -> lds+32768B (wf2 goes to lds+0)
    unsigned short (*st)[132] =
        (unsigned short (*)[132])(STAGE2 ? (void*)(wl + 16384) : (void*)wl);

    const int rl = wave * 16 + kq * 4;
#pragma unroll
    for (int oc = 0; oc < 8; oc++) {
        int o = oc * 16 + (lane & 15);
        float bv = bias[o];
#pragma unroll
        for (int j = 0; j < 4; j++) {
            float v = fmaxf(acc[oc][j] + bv, 0.0f);
            st[rl + j][o] = f2bf(v);
        }
    }
    if (STAGE2) {
        // stage wf2: 32 KB global -> LDS low half (8 x uint4 per thread)
        const uint4* srcw = (const uint4*)wf2;
        uint4* dstw = (uint4*)wl;
#pragma unroll
        for (int i = 0; i < 8; i++) dstw[t + i * 256] = srcw[t + i * 256];
    }
    __syncthreads();

    if (!STAGE2) {
        // coalesced fp8 h stores: 512 chunks of 16 B
#pragma unroll
        for (int i = 0; i < 2; i++) {
            int c = t + i * 256;
            int r = c >> 3;
            int pos = (c & 7) * 16;
            int node = bRow0 + r;
            if (node < N) {
                short8 v0 = *(const short8*)&st[r][pos];
                short8 v1 = *(const short8*)&st[r][pos + 8];
                *(uint4*)(outq + (size_t)node * 128 + pos) = pack16_fp8(v0, v1);
            }
        }
    } else {
        // ---- stage 2: layer-2 transform; A from st (h), B from LDS wf2 ----
        floatx4 acc2[8];
#pragma unroll
        for (int i = 0; i < 8; i++) acc2[i] = (floatx4)0.0f;
#pragma unroll
        for (int ks = 0; ks < 4; ks++) {
            short8 a = *(const short8*)&st[rloc][ks * 32 + kq * 8];
#pragma unroll
            for (int oc = 0; oc < 8; oc++) {
                short8 b = *(const short8*)&wl[((ks * 8 + oc) * 64 + lane) * 8];
                acc2[oc] = __builtin_amdgcn_mfma_f32_16x16x32_bf16(a, b, acc2[oc], 0, 0, 0);
            }
        }
        __syncthreads();  // done reading h (st) and wf2; safe to overwrite st
        const int o16 = lane & 15;
#pragma unroll
        for (int oc = 0; oc < 8; oc++) {
#pragma unroll
            for (int j = 0; j < 4; j++) {
                int node = bRow0 + wave * 16 + kq * 4 + j;
                if (oc < 4) {
                    st[rl + j][oc * 16 + o16] = f2bf(acc2[oc][j]);  // t2 tile (cols 0..63)
                } else if (node < N) {
                    int o = (oc - 4) * 16 + o16;
                    outf[(size_t)node * 64 + o] = acc2[oc][j] + bias2[o];  // self (full-line)
                }
            }
        }
        __syncthreads();
        // coalesced fp8 t2 stores: 256 chunks of 16 B (64 rows x 64 B)
        {
            int r = t >> 2;
            int pos = (t & 3) * 16;
            int node = bRow0 + r;
            if (node < N) {
                short8 v0 = *(const short8*)&st[r][pos];
                short8 v1 = *(const short8*)&st[r][pos + 8];
                *(uint4*)(t2q + (size_t)node * 64 + pos) = pack16_fp8(v0, v1);
            }
        }
    }
}

// 64-wide fp8 mean aggregation of t2 + add self + fused log_softmax (16-lane group/node)
__global__ __launch_bounds__(256) void k_aggr64lsm(const unsigned char* t2q, const int* rowptr,
                                                   const int* adj, float* out, int N) {
    int g = (blockIdx.x * blockDim.x + threadIdx.x) >> 4;
    int lane = threadIdx.x & 15;
    if (g >= N) return;
    int lo = rowptr[g], hi = rowptr[g + 1];
    float a0 = 0.f, a1 = 0.f, a2 = 0.f, a3 = 0.f;
    const unsigned char* fb = t2q + lane * 4;
    int j = lo;
    for (; j + 8 <= hi; j += 8) {
        unsigned int v[8];
#pragma unroll
        for (int u = 0; u < 8; u++) {
            int s = adj[j + u];
            v[u] = *(const unsigned int*)(fb + (size_t)s * 64);
        }
#pragma unroll
        for (int u = 0; u < 8; u++) {
            floatx2 l2 = fp8pk2f<false>(v[u]);
            floatx2 h2 = fp8pk2f<true>(v[u]);
            a0 += l2[0]; a1 += l2[1]; a2 += h2[0]; a3 += h2[1];
        }
    }
    if (j < hi) {
        unsigned int v[8];
        float w[8];
#pragma unroll
        for (int u = 0; u < 8; u++) {
            int jj = j + u;
            int s = adj[jj < hi ? jj : hi - 1];
            v[u] = *(const unsigned int*)(fb + (size_t)s * 64);
            w[u] = (jj < hi) ? 1.0f : 0.0f;
        }
#pragma unroll
        for (int u = 0; u < 8; u++) {
            floatx2 l2 = fp8pk2f<false>(v[u]);
            floatx2 h2 = fp8pk2f<true>(v[u]);
            a0 = fmaf(w[u], l2[0], a0);
            a1 = fmaf(w[u], l2[1], a1);
            a2 = fmaf(w[u], h2[0], a2);
            a3 = fmaf(w[u], h2[1], a3);
        }
    }
    float inv = 1.0f / (float)max(hi - lo, 1);
    float* op = out + (size_t)g * 64 + lane * 4;
    float4 cur = *(float4*)op;
    float v0 = cur.x + a0 * inv, v1 = cur.y + a1 * inv;
    float v2 = cur.z + a2 * inv, v3 = cur.w + a3 * inv;
    float m = fmaxf(fmaxf(v0, v1), fmaxf(v2, v3));
#pragma unroll
    for (int off = 8; off; off >>= 1) m = fmaxf(m, __shfl_xor(m, off));
    float s = expf(v0 - m) + expf(v1 - m) + expf(v2 - m) + expf(v3 - m);
#pragma unroll
    for (int off = 8; off; off >>= 1) s += __shfl_xor(s, off);
    float ls = m + logf(s);
    float4 o;
    o.x = v0 - ls; o.y = v1 - ls; o.z = v2 - ls; o.w = v3 - ls;
    *(float4*)op = o;
}

extern "C" void kernel_launch(void* const* d_in, const int* in_sizes, int n_in,
                              void* d_out, int out_size, void* d_ws, size_t ws_size,
                              hipStream_t stream) {
    const float* x = (const float*)d_in[0];
    const int* ei = (const int*)d_in[1];
    const float* Wl0 = (const float*)d_in[2];
    const float* bl0 = (const float*)d_in[3];
    const float* Wr0 = (const float*)d_in[4];
    const float* Wl1 = (const float*)d_in[5];
    const float* bl1 = (const float*)d_in[6];
    const float* Wr1 = (const float*)d_in[7];
    const float* Wl2 = (const float*)d_in[8];
    const float* bl2 = (const float*)d_in[9];
    const float* Wr2 = (const float*)d_in[10];

    const int N = in_sizes[0] / 128;
    const int E = in_sizes[1] / 2;
    const int* src = ei;
    const int* dst = ei + E;

    char* ws = (char*)d_ws;
    size_t off = 0;
    auto alloc = [&](size_t bytes) {
        void* p = ws + off;
        off += (bytes + 255) & ~(size_t)255;
        return p;
    };
    int* cntin = (int*)alloc((size_t)NB * B1 * 4);
    int* cntoff = (int*)alloc(((size_t)NB * B1 + 1) * 4);
    int* bsum = (int*)alloc(1024 * 4);
    unsigned int* ebuf = (unsigned int*)alloc((size_t)E * 4);
    int* rowptr = (int*)alloc((size_t)(N + 1) * 4);
    int* adj = (int*)alloc((size_t)E * 4);
    unsigned char* abuf = (unsigned char*)alloc((size_t)N * 128);  // fp8 aggr; reused as fp8 t2
    unsigned char* q8a = (unsigned char*)alloc((size_t)N * 128);   // fp8(x)
    unsigned char* q8b = (unsigned char*)alloc((size_t)N * 128);   // fp8(h0)
    unsigned short* w0 = (unsigned short*)alloc(8 * 8 * 64 * 8 * 2);
    unsigned short* w1 = (unsigned short*)alloc(8 * 8 * 64 * 8 * 2);
    unsigned short* w2 = (unsigned short*)alloc(4 * 8 * 64 * 8 * 2);

    // ---- bucketed CSR build ----
    const int NBUCK = (N + 255) >> 8;
    k_bhist<<<B1, 256, 0, stream>>>(dst, E, cntin);
    const int scanLen = NB * B1;
    const int nScanBlocks = (scanLen + SCAN_CHUNK - 1) / SCAN_CHUNK;
    k_scan_part<<<nScanBlocks, SCAN_T, 0, stream>>>(cntin, bsum, scanLen);
    k_scan_top<<<1, 64, 0, stream>>>(bsum, nScanBlocks);
    k_scan_apply<<<nScanBlocks, SCAN_T, 0, stream>>>(cntin, bsum, cntoff, scanLen);
    k_bscatter<<<B1, 256, 0, stream>>>(src, dst, E, cntoff, ebuf);
    k_build<<<NBUCK, 256, 0, stream>>>(ebuf, cntoff, rowptr, adj, N, E);

    // combined conversion + weight prep (one launch)
    const int cvtBlocks = ((N * 128 / 4) + 255) / 256;
    k_prep<<<cvtBlocks + 128 + 128 + 64, 256, 0, stream>>>(
        x, q8a, N * 128 / 4, Wl0, Wr0, w0, Wl1, Wr1, w1, Wl2, Wr2, w2, cvtBlocks);

    const int aggrGrid = ((N * 32) + 255) / 256;
    const int aggr64Grid = ((N * 16) + 255) / 256;
    const int xfGrid = (N + 63) / 64;

    unsigned char* aggr = abuf;
    unsigned char* t2q = abuf;

    // layer 0: gather fp8(x) -> fp8 mean; xform([aggr|x]) -> fp8(h0)
    k_aggr8<<<aggrGrid, 256, 0, stream>>>(q8a, rowptr, adj, aggr, N);
    k_xform<false><<<xfGrid, 256, 0, stream>>>(aggr, q8a, w0, bl0, q8b,
                                               nullptr, nullptr, nullptr, nullptr, N);
    // layer 1: gather fp8(h0) -> fp8 mean; xform([aggr|h0]) -> h1 (LDS only)
    //          + fused layer-2 transform: t2q (fp8) + self (f32 -> d_out)
    k_aggr8<<<aggrGrid, 256, 0, stream>>>(q8b, rowptr, adj, aggr, N);
    k_xform<true><<<xfGrid, 256, 0, stream>>>(aggr, q8b, w1, bl1, nullptr,
                                              w2, bl2, t2q, (float*)d_out, N);
    // layer 2 aggregation: fused fp8 aggregate + log_softmax
    k_aggr64lsm<<<aggr64Grid, 256, 0, stream>>>(t2q, rowptr, adj, (float*)d_out, N);
}

// Round 16
// 232.391 us; speedup vs baseline: 1.0390x; 1.0390x over previous
//
#include <hip/hip_runtime.h>
#include <hip/hip_bf16.h>
#include <math.h>

typedef __attribute__((ext_vector_type(8))) short short8;
typedef __attribute__((ext_vector_type(4))) float floatx4;
typedef __attribute__((ext_vector_type(2))) float floatx2;
typedef __attribute__((ext_vector_type(4))) unsigned short ushortx4;

__device__ __forceinline__ float bf2f(unsigned short u) {
    union { unsigned int i; float f; } c; c.i = ((unsigned int)u) << 16; return c.f;
}
__device__ __forceinline__ unsigned short f2bf(float f) {
    union { float f; unsigned int i; } c; c.f = f;
    unsigned int x = c.i;
    return (unsigned short)((x + 0x7FFFu + ((x >> 16) & 1u)) >> 16);
}

// ---------- fp8 e4m3fn (OCP) encode/decode ----------
__device__ __forceinline__ unsigned char f2fp8(float f) {
    unsigned int u = __float_as_uint(f);
    unsigned int sign = (u >> 24) & 0x80u;
    unsigned int a = u & 0x7FFFFFFFu;
    if (a >= 0x43E00000u) return (unsigned char)(sign | 0x7Eu);  // saturate at 448
    if (a < 0x3C800000u) {  // below smallest normal 2^-6: denormal units of 2^-9
        int unit = (int)rintf(__uint_as_float(a) * 512.0f);
        return (unsigned char)(sign | (unsigned int)unit);
    }
    unsigned int r = a + 0x7FFFFu + ((a >> 20) & 1u);  // RNE at bit 20
    unsigned int e = (r >> 23) - 120u;
    unsigned int m = (r >> 20) & 7u;
    return (unsigned char)(sign | (e << 3) | m);
}

__device__ __forceinline__ float fp8dec1(unsigned int b) {
    unsigned int s = (b & 0x80u) << 24;
    unsigned int mag = (b & 0x7Fu) << 20;
    return __uint_as_float(s | mag) * __uint_as_float(0x7B800000u);  // * 2^120
}

template <bool W>
__device__ __forceinline__ floatx2 fp8pk2f(unsigned int v) {
#if defined(__has_builtin) && __has_builtin(__builtin_amdgcn_cvt_pk_f32_fp8)
    return __builtin_amdgcn_cvt_pk_f32_fp8(v, W);
#else
    floatx2 r;
    r[0] = fp8dec1((v >> (W ? 16 : 0)) & 0xFFu);
    r[1] = fp8dec1((v >> (W ? 24 : 8)) & 0xFFu);
    return r;
#endif
}

// pack 16 bf16 (two short8) -> 16 fp8 bytes as uint4
__device__ __forceinline__ uint4 pack16_fp8(short8 v0, short8 v1) {
    unsigned int w[4];
#pragma unroll
    for (int q = 0; q < 2; q++) {
        w[q] = (unsigned int)f2fp8(bf2f((unsigned short)v0[q * 4 + 0])) |
               ((unsigned int)f2fp8(bf2f((unsigned short)v0[q * 4 + 1])) << 8) |
               ((unsigned int)f2fp8(bf2f((unsigned short)v0[q * 4 + 2])) << 16) |
               ((unsigned int)f2fp8(bf2f((unsigned short)v0[q * 4 + 3])) << 24);
        w[q + 2] = (unsigned int)f2fp8(bf2f((unsigned short)v1[q * 4 + 0])) |
                   ((unsigned int)f2fp8(bf2f((unsigned short)v1[q * 4 + 1])) << 8) |
                   ((unsigned int)f2fp8(bf2f((unsigned short)v1[q * 4 + 2])) << 16) |
                   ((unsigned int)f2fp8(bf2f((unsigned short)v1[q * 4 + 3])) << 24);
    }
    uint4 u;
    u.x = w[0]; u.y = w[1]; u.z = w[2]; u.w = w[3];
    return u;
}

// ================= bucketed CSR build =================
constexpr int NB = 512;
constexpr int B1 = 256;

__global__ __launch_bounds__(256) void k_bhist(const int* dst, int E, int* cnt) {
    __shared__ int h[NB];
    int t = threadIdx.x, b = blockIdx.x;
    h[t] = 0; h[t + 256] = 0;
    __syncthreads();
    int chunk = (E + B1 - 1) / B1;
    int lo = b * chunk, hi = min(E, lo + chunk);
    for (int e = lo + t; e < hi; e += 256) atomicAdd(&h[dst[e] >> 8], 1);
    __syncthreads();
    cnt[(size_t)t * B1 + b] = h[t];
    cnt[(size_t)(t + 256) * B1 + b] = h[t + 256];
}

constexpr int SCAN_T = 256;
constexpr int SCAN_V = 8;
constexpr int SCAN_CHUNK = SCAN_T * SCAN_V;

__global__ void k_scan_part(const int* in, int* bsum, int N) {
    int b = blockIdx.x, t = threadIdx.x;
    int base = b * SCAN_CHUNK + t * SCAN_V;
    int s = 0;
#pragma unroll
    for (int j = 0; j < SCAN_V; j++) {
        int i = base + j;
        if (i < N) s += in[i];
    }
    __shared__ int wsums[SCAN_T / 64];
    for (int off = 32; off; off >>= 1) s += __shfl_down(s, off, 64);
    if ((t & 63) == 0) wsums[t >> 6] = s;
    __syncthreads();
    if (t == 0) {
        int tot = 0;
#pragma unroll
        for (int w = 0; w < SCAN_T / 64; w++) tot += wsums[w];
        bsum[b] = tot;
    }
}

__global__ void k_scan_top(int* bsum, int nb) {
    if (threadIdx.x == 0) {
        int run = 0;
        for (int i = 0; i < nb; i++) {
            int v = bsum[i];
            bsum[i] = run;
            run += v;
        }
    }
}

__global__ void k_scan_apply(const int* in, const int* bsum, int* out, int N) {
    int b = blockIdx.x, t = threadIdx.x;
    int base = b * SCAN_CHUNK + t * SCAN_V;
    int v[SCAN_V];
    int s = 0;
#pragma unroll
    for (int j = 0; j < SCAN_V; j++) {
        int i = base + j;
        v[j] = (i < N) ? in[i] : 0;
        s += v[j];
    }
    __shared__ int sums[SCAN_T];
    sums[t] = s;
    __syncthreads();
    for (int off = 1; off < SCAN_T; off <<= 1) {
        int x = (t >= off) ? sums[t - off] : 0;
        __syncthreads();
        sums[t] += x;
        __syncthreads();
    }
    int pre = bsum[b] + ((t == 0) ? 0 : sums[t - 1]);
#pragma unroll
    for (int j = 0; j < SCAN_V; j++) {
        int i = base + j;
        if (i < N) {
            out[i] = pre;
            pre += v[j];
            if (i == N - 1) out[N] = pre;
        }
    }
}

__global__ __launch_bounds__(256) void k_bscatter(const int* src, const int* dst, int E,
                                                  const int* cntoff, unsigned int* ebuf) {
    __shared__ int base[NB];
    __shared__ int lcur[NB];
    int t = threadIdx.x, b = blockIdx.x;
    for (int i = t; i < NB; i += 256) {
        base[i] = cntoff[(size_t)i * B1 + b];
        lcur[i] = 0;
    }
    __syncthreads();
    int chunk = (E + B1 - 1) / B1;
    int lo = b * chunk, hi = min(E, lo + chunk);
    for (int e = lo + t; e < hi; e += 256) {
        int d = dst[e];
        int cb = d >> 8;
        int slot = atomicAdd(&lcur[cb], 1);
        ebuf[base[cb] + slot] = (unsigned int)src[e] | ((unsigned int)(d & 255) << 17);
    }
}

__global__ __launch_bounds__(256) void k_build(const unsigned int* ebuf, const int* cntoff,
                                               int* rowptr, int* adj, int N, int E) {
    __shared__ int ldeg[256];
    __shared__ int lptr[256];
    __shared__ int lcur[256];
    __shared__ int tsum[256];
    int t = threadIdx.x, cb = blockIdx.x;
    int bbase = cntoff[(size_t)cb * B1];
    int bend = cntoff[(size_t)(cb + 1) * B1];
    ldeg[t] = 0;
    lcur[t] = 0;
    __syncthreads();
    for (int e = bbase + t; e < bend; e += 256) atomicAdd(&ldeg[ebuf[e] >> 17], 1);
    __syncthreads();
    tsum[t] = ldeg[t];
    __syncthreads();
    for (int off = 1; off < 256; off <<= 1) {
        int v = (t >= off) ? tsum[t - off] : 0;
        __syncthreads();
        tsum[t] += v;
        __syncthreads();
    }
    lptr[t] = tsum[t] - ldeg[t];
    __syncthreads();
    int node = cb * 256 + t;
    if (node < N) rowptr[node] = bbase + lptr[t];
    if (cb == 0 && t == 0) rowptr[N] = E;
    for (int e = bbase + t; e < bend; e += 256) {
        unsigned int pk = ebuf[e];
        int dl = pk >> 17;
        int ls = atomicAdd(&lcur[dl], 1);
        adj[bbase + lptr[dl] + ls] = (int)(pk & 0x1FFFF);
    }
}

// ---------------- combined prep: x->fp8 AND weight prep (W0/W1 fp8, W2 bf16) ----------------
// fp8 weight fragments for mfma_f32_16x16x32_fp8_fp8: byte t = f2fp8(W[k][o]),
// k = ks*32 + (lane>>4)*8 + j, o = oc*16 + (lane&15); t = ((ks*8+oc)*64+lane)*8 + j
__device__ __forceinline__ void prep_w8_body(const float* Wl, const float* Wr,
                                             unsigned char* wf, int t) {
    int total = 8 * 8 * 64 * 8;
    if (t >= total) return;
    int j = t & 7;
    int lane = (t >> 3) & 63;
    int rest = t >> 9;
    int oc = rest % 8;
    int ks = rest / 8;
    int k = ks * 32 + ((lane >> 4) << 3) + j;
    int o = oc * 16 + (lane & 15);
    float v = (k < 128) ? Wl[o * 128 + k] : Wr[o * 128 + (k - 128)];
    wf[t] = f2fp8(v);
}

// layer-2 weights (bf16): K=128, 8 out blocks (0..3 = Wl2 -> t2, 4..7 = Wr2 -> self)
__device__ __forceinline__ void prep_w2_body(const float* Wl, const float* Wr,
                                             unsigned short* wf, int t) {
    int total = 4 * 8 * 64 * 8;
    if (t >= total) return;
    int j = t & 7;
    int lane = (t >> 3) & 63;
    int rest = t >> 9;
    int oc = rest % 8;
    int ks = rest / 8;
    int k = ks * 32 + ((lane >> 4) << 3) + j;
    int o16 = lane & 15;
    float v = (oc < 4) ? Wl[(oc * 16 + o16) * 128 + k] : Wr[((oc - 4) * 16 + o16) * 128 + k];
    wf[t] = f2bf(v);
}

__global__ __launch_bounds__(256) void k_prep(const float* x, unsigned char* xq, int n4,
                                              const float* Wl0, const float* Wr0, unsigned char* w0,
                                              const float* Wl1, const float* Wr1, unsigned char* w1,
                                              const float* Wl2, const float* Wr2, unsigned short* w2,
                                              int cvtBlocks) {
    int b = blockIdx.x;
    if (b < cvtBlocks) {
        int i = b * 256 + threadIdx.x;
        int idx = i * 4;
        if (idx < n4 * 4) {
            float4 v = *(const float4*)(x + idx);
            unsigned int qw = (unsigned int)f2fp8(v.x) | ((unsigned int)f2fp8(v.y) << 8) |
                              ((unsigned int)f2fp8(v.z) << 16) | ((unsigned int)f2fp8(v.w) << 24);
            *(unsigned int*)(xq + idx) = qw;
        }
    } else if (b < cvtBlocks + 128) {
        prep_w8_body(Wl0, Wr0, w0, (b - cvtBlocks) * 256 + threadIdx.x);
    } else if (b < cvtBlocks + 256) {
        prep_w8_body(Wl1, Wr1, w1, (b - cvtBlocks - 128) * 256 + threadIdx.x);
    } else {
        prep_w2_body(Wl2, Wr2, w2, (b - cvtBlocks - 256) * 256 + threadIdx.x);
    }
}

// ---------------- fp8 mean aggregation -> fp8 mean (32-lane group per node) ----------------
__global__ __launch_bounds__(256) void k_aggr8(const unsigned char* feat, const int* rowptr,
                                               const int* adj, unsigned char* aggr, int N) {
    int g = (blockIdx.x * blockDim.x + threadIdx.x) >> 5;
    int lane = threadIdx.x & 31;
    if (g >= N) return;
    int lo = rowptr[g], hi = rowptr[g + 1];
    float a0 = 0.f, a1 = 0.f, a2 = 0.f, a3 = 0.f;
    const unsigned char* fb = feat + lane * 4;
    int j = lo;
    for (; j + 8 <= hi; j += 8) {
        unsigned int v[8];
#pragma unroll
        for (int u = 0; u < 8; u++) {
            int s = adj[j + u];
            v[u] = *(const unsigned int*)(fb + (size_t)s * 128);
        }
#pragma unroll
        for (int u = 0; u < 8; u++) {
            floatx2 l2 = fp8pk2f<false>(v[u]);
            floatx2 h2 = fp8pk2f<true>(v[u]);
            a0 += l2[0]; a1 += l2[1]; a2 += h2[0]; a3 += h2[1];
        }
    }
    if (j < hi) {  // masked tail chunk: loads issued back-to-back
        unsigned int v[8];
        float w[8];
#pragma unroll
        for (int u = 0; u < 8; u++) {
            int jj = j + u;
            int s = adj[jj < hi ? jj : hi - 1];
            v[u] = *(const unsigned int*)(fb + (size_t)s * 128);
            w[u] = (jj < hi) ? 1.0f : 0.0f;
        }
#pragma unroll
        for (int u = 0; u < 8; u++) {
            floatx2 l2 = fp8pk2f<false>(v[u]);
            floatx2 h2 = fp8pk2f<true>(v[u]);
            a0 = fmaf(w[u], l2[0], a0);
            a1 = fmaf(w[u], l2[1], a1);
            a2 = fmaf(w[u], h2[0], a2);
            a3 = fmaf(w[u], h2[1], a3);
        }
    }
    float inv = 1.0f / (float)max(hi - lo, 1);
    unsigned int qw = (unsigned int)f2fp8(a0 * inv) | ((unsigned int)f2fp8(a1 * inv) << 8) |
                      ((unsigned int)f2fp8(a2 * inv) << 16) | ((unsigned int)f2fp8(a3 * inv) << 24);
    *(unsigned int*)(aggr + (size_t)g * 128 + lane * 4) = qw;
}

// ---------------- fused transform: h = relu([aggr|feat] @ W + b), native fp8 MFMA ----------------
// A = fp8 activations loaded directly (no decode); B = fp8 weights (32 KB, L1-resident).
// STAGE2=false: write fp8(h) -> outq.
// STAGE2=true (layer 1): keep h in LDS (bf16); layer-2 with bf16 MFMA + bf16 W2:
//   t2 = h @ Wl2^T (fp8 -> t2q), self = h @ Wr2^T + bl2 (f32 -> outf).
template <bool STAGE2>
__global__ __launch_bounds__(256) void k_xform(const unsigned char* aggr,
                                               const unsigned char* featq,
                                               const unsigned char* w8,
                                               const float* bias, unsigned char* outq,
                                               const unsigned short* wf2, const float* bias2,
                                               unsigned char* t2q, float* outf, int N) {
    __shared__ unsigned short st[64][132];
    const int t = threadIdx.x;
    const int wave = t >> 6;
    const int lane = t & 63;
    const int rloc = wave * 16 + (lane & 15);
    const int bRow0 = blockIdx.x * 64;
    const int row = bRow0 + rloc;
    const int kq = lane >> 4;
    floatx4 acc[8];
#pragma unroll
    for (int i = 0; i < 8; i++) acc[i] = (floatx4)0.0f;
    const bool rowOK = row < N;
    const unsigned char* arow = aggr + (size_t)row * 128;
    const unsigned char* frow = featq + (size_t)row * 128;
    const long* bbase = (const long*)w8;
#pragma unroll
    for (int ks = 0; ks < 8; ks++) {
        long a;
        if (!rowOK) {
            a = 0;
        } else {
            const unsigned char* p =
                (ks < 4) ? (arow + ks * 32 + kq * 8) : (frow + (ks - 4) * 32 + kq * 8);
            a = *(const long*)p;
        }
#pragma unroll
        for (int oc = 0; oc < 8; oc++) {
            acc[oc] = __builtin_amdgcn_mfma_f32_16x16x32_fp8_fp8(
                a, bbase[(ks * 8 + oc) * 64 + lane], acc[oc], 0, 0, 0);
        }
    }
    const int rl = wave * 16 + kq * 4;
#pragma unroll
    for (int oc = 0; oc < 8; oc++) {
        int o = oc * 16 + (lane & 15);
        float bv = bias[o];
#pragma unroll
        for (int j = 0; j < 4; j++) {
            float v = fmaxf(acc[oc][j] + bv, 0.0f);
            st[rl + j][o] = f2bf(v);
        }
    }
    __syncthreads();
    if (!STAGE2) {
        // coalesced fp8 h stores: 512 chunks of 16 B
#pragma unroll
        for (int i = 0; i < 2; i++) {
            int c = t + i * 256;
            int r = c >> 3;
            int pos = (c & 7) * 16;
            int node = bRow0 + r;
            if (node < N) {
                short8 v0 = *(const short8*)&st[r][pos];
                short8 v1 = *(const short8*)&st[r][pos + 8];
                *(uint4*)(outq + (size_t)node * 128 + pos) = pack16_fp8(v0, v1);
            }
        }
    } else {
        // ---- stage 2: layer-2 transform from LDS h-tile (bf16 MFMA, bf16 W2) ----
        floatx4 acc2[8];
#pragma unroll
        for (int i = 0; i < 8; i++) acc2[i] = (floatx4)0.0f;
        const short8* bbase2 = (const short8*)wf2;
#pragma unroll
        for (int ks = 0; ks < 4; ks++) {
            short8 a = *(const short8*)&st[rloc][ks * 32 + kq * 8];
#pragma unroll
            for (int oc = 0; oc < 8; oc++) {
                short8 b = bbase2[(ks * 8 + oc) * 64 + lane];
                acc2[oc] = __builtin_amdgcn_mfma_f32_16x16x32_bf16(a, b, acc2[oc], 0, 0, 0);
            }
        }
        __syncthreads();  // done reading h from st; safe to overwrite
        const int o16 = lane & 15;
#pragma unroll
        for (int oc = 0; oc < 8; oc++) {
#pragma unroll
            for (int j = 0; j < 4; j++) {
                int node = bRow0 + wave * 16 + kq * 4 + j;
                if (oc < 4) {
                    st[rl + j][oc * 16 + o16] = f2bf(acc2[oc][j]);  // t2 tile (cols 0..63)
                } else if (node < N) {
                    int o = (oc - 4) * 16 + o16;
                    outf[(size_t)node * 64 + o] = acc2[oc][j] + bias2[o];  // self (full-line)
                }
            }
        }
        __syncthreads();
        // coalesced fp8 t2 stores: 256 chunks of 16 B (64 rows x 64 B)
        {
            int r = t >> 2;
            int pos = (t & 3) * 16;
            int node = bRow0 + r;
            if (node < N) {
                short8 v0 = *(const short8*)&st[r][pos];
                short8 v1 = *(const short8*)&st[r][pos + 8];
                *(uint4*)(t2q + (size_t)node * 64 + pos) = pack16_fp8(v0, v1);
            }
        }
    }
}

// 64-wide fp8 mean aggregation of t2 + add self + fused log_softmax (16-lane group/node)
__global__ __launch_bounds__(256) void k_aggr64lsm(const unsigned char* t2q, const int* rowptr,
                                                   const int* adj, float* out, int N) {
    int g = (blockIdx.x * blockDim.x + threadIdx.x) >> 4;
    int lane = threadIdx.x & 15;
    if (g >= N) return;
    int lo = rowptr[g], hi = rowptr[g + 1];
    float a0 = 0.f, a1 = 0.f, a2 = 0.f, a3 = 0.f;
    const unsigned char* fb = t2q + lane * 4;
    int j = lo;
    for (; j + 8 <= hi; j += 8) {
        unsigned int v[8];
#pragma unroll
        for (int u = 0; u < 8; u++) {
            int s = adj[j + u];
            v[u] = *(const unsigned int*)(fb + (size_t)s * 64);
        }
#pragma unroll
        for (int u = 0; u < 8; u++) {
            floatx2 l2 = fp8pk2f<false>(v[u]);
            floatx2 h2 = fp8pk2f<true>(v[u]);
            a0 += l2[0]; a1 += l2[1]; a2 += h2[0]; a3 += h2[1];
        }
    }
    if (j < hi) {
        unsigned int v[8];
        float w[8];
#pragma unroll
        for (int u = 0; u < 8; u++) {
            int jj = j + u;
            int s = adj[jj < hi ? jj : hi - 1];
            v[u] = *(const unsigned int*)(fb + (size_t)s * 64);
            w[u] = (jj < hi) ? 1.0f : 0.0f;
        }
#pragma unroll
        for (int u = 0; u < 8; u++) {
            floatx2 l2 = fp8pk2f<false>(v[u]);
            floatx2 h2 = fp8pk2f<true>(v[u]);
            a0 = fmaf(w[u], l2[0], a0);
            a1 = fmaf(w[u], l2[1], a1);
            a2 = fmaf(w[u], h2[0], a2);
            a3 = fmaf(w[u], h2[1], a3);
        }
    }
    float inv = 1.0f / (float)max(hi - lo, 1);
    float* op = out + (size_t)g * 64 + lane * 4;
    float4 cur = *(float4*)op;
    float v0 = cur.x + a0 * inv, v1 = cur.y + a1 * inv;
    float v2 = cur.z + a2 * inv, v3 = cur.w + a3 * inv;
    float m = fmaxf(fmaxf(v0, v1), fmaxf(v2, v3));
#pragma unroll
    for (int off = 8; off; off >>= 1) m = fmaxf(m, __shfl_xor(m, off));
    float s = expf(v0 - m) + expf(v1 - m) + expf(v2 - m) + expf(v3 - m);
#pragma unroll
    for (int off = 8; off; off >>= 1) s += __shfl_xor(s, off);
    float ls = m + logf(s);
    float4 o;
    o.x = v0 - ls; o.y = v1 - ls; o.z = v2 - ls; o.w = v3 - ls;
    *(float4*)op = o;
}

extern "C" void kernel_launch(void* const* d_in, const int* in_sizes, int n_in,
                              void* d_out, int out_size, void* d_ws, size_t ws_size,
                              hipStream_t stream) {
    const float* x = (const float*)d_in[0];
    const int* ei = (const int*)d_in[1];
    const float* Wl0 = (const float*)d_in[2];
    const float* bl0 = (const float*)d_in[3];
    const float* Wr0 = (const float*)d_in[4];
    const float* Wl1 = (const float*)d_in[5];
    const float* bl1 = (const float*)d_in[6];
    const float* Wr1 = (const float*)d_in[7];
    const float* Wl2 = (const float*)d_in[8];
    const float* bl2 = (const float*)d_in[9];
    const float* Wr2 = (const float*)d_in[10];

    const int N = in_sizes[0] / 128;
    const int E = in_sizes[1] / 2;
    const int* src = ei;
    const int* dst = ei + E;

    char* ws = (char*)d_ws;
    size_t off = 0;
    auto alloc = [&](size_t bytes) {
        void* p = ws + off;
        off += (bytes + 255) & ~(size_t)255;
        return p;
    };
    int* cntin = (int*)alloc((size_t)NB * B1 * 4);
    int* cntoff = (int*)alloc(((size_t)NB * B1 + 1) * 4);
    int* bsum = (int*)alloc(1024 * 4);
    unsigned int* ebuf = (unsigned int*)alloc((size_t)E * 4);
    int* rowptr = (int*)alloc((size_t)(N + 1) * 4);
    int* adj = (int*)alloc((size_t)E * 4);
    unsigned char* abuf = (unsigned char*)alloc((size_t)N * 128);  // fp8 aggr; reused as fp8 t2
    unsigned char* q8a = (unsigned char*)alloc((size_t)N * 128);   // fp8(x)
    unsigned char* q8b = (unsigned char*)alloc((size_t)N * 128);   // fp8(h0)
    unsigned char* w0 = (unsigned char*)alloc(8 * 8 * 64 * 8);     // fp8 weights L0 (32 KB)
    unsigned char* w1 = (unsigned char*)alloc(8 * 8 * 64 * 8);     // fp8 weights L1 (32 KB)
    unsigned short* w2 = (unsigned short*)alloc(4 * 8 * 64 * 8 * 2);  // bf16 weights L2

    // ---- bucketed CSR build ----
    const int NBUCK = (N + 255) >> 8;
    k_bhist<<<B1, 256, 0, stream>>>(dst, E, cntin);
    const int scanLen = NB * B1;
    const int nScanBlocks = (scanLen + SCAN_CHUNK - 1) / SCAN_CHUNK;
    k_scan_part<<<nScanBlocks, SCAN_T, 0, stream>>>(cntin, bsum, scanLen);
    k_scan_top<<<1, 64, 0, stream>>>(bsum, nScanBlocks);
    k_scan_apply<<<nScanBlocks, SCAN_T, 0, stream>>>(cntin, bsum, cntoff, scanLen);
    k_bscatter<<<B1, 256, 0, stream>>>(src, dst, E, cntoff, ebuf);
    k_build<<<NBUCK, 256, 0, stream>>>(ebuf, cntoff, rowptr, adj, N, E);

    // combined conversion + weight prep (one launch)
    const int cvtBlocks = ((N * 128 / 4) + 255) / 256;
    k_prep<<<cvtBlocks + 128 + 128 + 64, 256, 0, stream>>>(
        x, q8a, N * 128 / 4, Wl0, Wr0, w0, Wl1, Wr1, w1, Wl2, Wr2, w2, cvtBlocks);

    const int aggrGrid = ((N * 32) + 255) / 256;
    const int aggr64Grid = ((N * 16) + 255) / 256;
    const int xfGrid = (N + 63) / 64;

    unsigned char* aggr = abuf;
    unsigned char* t2q = abuf;

    // layer 0: gather fp8(x) -> fp8 mean; xform([aggr|x]) -> fp8(h0)
    k_aggr8<<<aggrGrid, 256, 0, stream>>>(q8a, rowptr, adj, aggr, N);
    k_xform<false><<<xfGrid, 256, 0, stream>>>(aggr, q8a, w0, bl0, q8b,
                                               nullptr, nullptr, nullptr, nullptr, N);
    // layer 1: gather fp8(h0) -> fp8 mean; xform([aggr|h0]) -> h1 (LDS only)
    //          + fused layer-2 transform: t2q (fp8) + self (f32 -> d_out)
    k_aggr8<<<aggrGrid, 256, 0, stream>>>(q8b, rowptr, adj, aggr, N);
    k_xform<true><<<xfGrid, 256, 0, stream>>>(aggr, q8b, w1, bl1, nullptr,
                                              w2, bl2, t2q, (float*)d_out, N);
    // layer 2 aggregation: fused fp8 aggregate + log_softmax
    k_aggr64lsm<<<aggr64Grid, 256, 0, stream>>>(t2q, rowptr, adj, (float*)d_out, N);
}

// Round 17
// 218.176 us; speedup vs baseline: 1.1067x; 1.0652x over previous
//
#include <hip/hip_runtime.h>
#include <hip/hip_bf16.h>
#include <math.h>

typedef __attribute__((ext_vector_type(8))) short short8;
typedef __attribute__((ext_vector_type(4))) float floatx4;
typedef __attribute__((ext_vector_type(2))) float floatx2;
typedef __attribute__((ext_vector_type(4))) unsigned short ushortx4;

__device__ __forceinline__ float bf2f(unsigned short u) {
    union { unsigned int i; float f; } c; c.i = ((unsigned int)u) << 16; return c.f;
}
__device__ __forceinline__ unsigned short f2bf(float f) {
    union { float f; unsigned int i; } c; c.f = f;
    unsigned int x = c.i;
    return (unsigned short)((x + 0x7FFFu + ((x >> 16) & 1u)) >> 16);
}

// ---------- fp8 e4m3fn (OCP) encode/decode ----------
__device__ __forceinline__ unsigned char f2fp8(float f) {
    unsigned int u = __float_as_uint(f);
    unsigned int sign = (u >> 24) & 0x80u;
    unsigned int a = u & 0x7FFFFFFFu;
    if (a >= 0x43E00000u) return (unsigned char)(sign | 0x7Eu);  // saturate at 448
    if (a < 0x3C800000u) {  // below smallest normal 2^-6: denormal units of 2^-9
        int unit = (int)rintf(__uint_as_float(a) * 512.0f);
        return (unsigned char)(sign | (unsigned int)unit);
    }
    unsigned int r = a + 0x7FFFFu + ((a >> 20) & 1u);  // RNE at bit 20
    unsigned int e = (r >> 23) - 120u;
    unsigned int m = (r >> 20) & 7u;
    return (unsigned char)(sign | (e << 3) | m);
}

// pack 4 floats -> 4 fp8 bytes (HW cvt where available; RNE)
__device__ __forceinline__ unsigned int cvtpk4_fp8(float a, float b, float c, float d) {
#if defined(__has_builtin) && __has_builtin(__builtin_amdgcn_cvt_pk_fp8_f32)
    int r = 0;
    r = __builtin_amdgcn_cvt_pk_fp8_f32(a, b, r, false);  // bytes 0,1
    r = __builtin_amdgcn_cvt_pk_fp8_f32(c, d, r, true);   // bytes 2,3
    return (unsigned int)r;
#else
    return (unsigned int)f2fp8(a) | ((unsigned int)f2fp8(b) << 8) |
           ((unsigned int)f2fp8(c) << 16) | ((unsigned int)f2fp8(d) << 24);
#endif
}

__device__ __forceinline__ float fp8dec1(unsigned int b) {
    unsigned int s = (b & 0x80u) << 24;
    unsigned int mag = (b & 0x7Fu) << 20;
    return __uint_as_float(s | mag) * __uint_as_float(0x7B800000u);  // * 2^120
}

template <bool W>
__device__ __forceinline__ floatx2 fp8pk2f(unsigned int v) {
#if defined(__has_builtin) && __has_builtin(__builtin_amdgcn_cvt_pk_f32_fp8)
    return __builtin_amdgcn_cvt_pk_f32_fp8(v, W);
#else
    floatx2 r;
    r[0] = fp8dec1((v >> (W ? 16 : 0)) & 0xFFu);
    r[1] = fp8dec1((v >> (W ? 24 : 8)) & 0xFFu);
    return r;
#endif
}

// pack 16 bf16 (two short8) -> 16 fp8 bytes as uint4 (HW cvt)
__device__ __forceinline__ uint4 pack16_fp8(short8 v0, short8 v1) {
    uint4 u;
    u.x = cvtpk4_fp8(bf2f((unsigned short)v0[0]), bf2f((unsigned short)v0[1]),
                     bf2f((unsigned short)v0[2]), bf2f((unsigned short)v0[3]));
    u.y = cvtpk4_fp8(bf2f((unsigned short)v0[4]), bf2f((unsigned short)v0[5]),
                     bf2f((unsigned short)v0[6]), bf2f((unsigned short)v0[7]));
    u.z = cvtpk4_fp8(bf2f((unsigned short)v1[0]), bf2f((unsigned short)v1[1]),
                     bf2f((unsigned short)v1[2]), bf2f((unsigned short)v1[3]));
    u.w = cvtpk4_fp8(bf2f((unsigned short)v1[4]), bf2f((unsigned short)v1[5]),
                     bf2f((unsigned short)v1[6]), bf2f((unsigned short)v1[7]));
    return u;
}

// ================= bucketed CSR build =================
constexpr int NB = 512;
constexpr int B1 = 256;

__global__ __launch_bounds__(256) void k_bhist(const int* dst, int E, int* cnt) {
    __shared__ int h[NB];
    int t = threadIdx.x, b = blockIdx.x;
    h[t] = 0; h[t + 256] = 0;
    __syncthreads();
    int chunk = (E + B1 - 1) / B1;
    int lo = b * chunk, hi = min(E, lo + chunk);
    for (int e = lo + t; e < hi; e += 256) atomicAdd(&h[dst[e] >> 8], 1);
    __syncthreads();
    cnt[(size_t)t * B1 + b] = h[t];
    cnt[(size_t)(t + 256) * B1 + b] = h[t + 256];
}

constexpr int SCAN_T = 256;
constexpr int SCAN_V = 8;
constexpr int SCAN_CHUNK = SCAN_T * SCAN_V;

__global__ void k_scan_part(const int* in, int* bsum, int N) {
    int b = blockIdx.x, t = threadIdx.x;
    int base = b * SCAN_CHUNK + t * SCAN_V;
    int s = 0;
#pragma unroll
    for (int j = 0; j < SCAN_V; j++) {
        int i = base + j;
        if (i < N) s += in[i];
    }
    __shared__ int wsums[SCAN_T / 64];
    for (int off = 32; off; off >>= 1) s += __shfl_down(s, off, 64);
    if ((t & 63) == 0) wsums[t >> 6] = s;
    __syncthreads();
    if (t == 0) {
        int tot = 0;
#pragma unroll
        for (int w = 0; w < SCAN_T / 64; w++) tot += wsums[w];
        bsum[b] = tot;
    }
}

__global__ void k_scan_top(int* bsum, int nb) {
    if (threadIdx.x == 0) {
        int run = 0;
        for (int i = 0; i < nb; i++) {
            int v = bsum[i];
            bsum[i] = run;
            run += v;
        }
    }
}

__global__ void k_scan_apply(const int* in, const int* bsum, int* out, int N) {
    int b = blockIdx.x, t = threadIdx.x;
    int base = b * SCAN_CHUNK + t * SCAN_V;
    int v[SCAN_V];
    int s = 0;
#pragma unroll
    for (int j = 0; j < SCAN_V; j++) {
        int i = base + j;
        v[j] = (i < N) ? in[i] : 0;
        s += v[j];
    }
    __shared__ int sums[SCAN_T];
    sums[t] = s;
    __syncthreads();
    for (int off = 1; off < SCAN_T; off <<= 1) {
        int x = (t >= off) ? sums[t - off] : 0;
        __syncthreads();
        sums[t] += x;
        __syncthreads();
    }
    int pre = bsum[b] + ((t == 0) ? 0 : sums[t - 1]);
#pragma unroll
    for (int j = 0; j < SCAN_V; j++) {
        int i = base + j;
        if (i < N) {
            out[i] = pre;
            pre += v[j];
            if (i == N - 1) out[N] = pre;
        }
    }
}

__global__ __launch_bounds__(256) void k_bscatter(const int* src, const int* dst, int E,
                                                  const int* cntoff, unsigned int* ebuf) {
    __shared__ int base[NB];
    __shared__ int lcur[NB];
    int t = threadIdx.x, b = blockIdx.x;
    for (int i = t; i < NB; i += 256) {
        base[i] = cntoff[(size_t)i * B1 + b];
        lcur[i] = 0;
    }
    __syncthreads();
    int chunk = (E + B1 - 1) / B1;
    int lo = b * chunk, hi = min(E, lo + chunk);
    for (int e = lo + t; e < hi; e += 256) {
        int d = dst[e];
        int cb = d >> 8;
        int slot = atomicAdd(&lcur[cb], 1);
        ebuf[base[cb] + slot] = (unsigned int)src[e] | ((unsigned int)(d & 255) << 17);
    }
}

__global__ __launch_bounds__(256) void k_build(const unsigned int* ebuf, const int* cntoff,
                                               int* rowptr, int* adj, int N, int E) {
    __shared__ int ldeg[256];
    __shared__ int lptr[256];
    __shared__ int lcur[256];
    __shared__ int tsum[256];
    int t = threadIdx.x, cb = blockIdx.x;
    int bbase = cntoff[(size_t)cb * B1];
    int bend = cntoff[(size_t)(cb + 1) * B1];
    ldeg[t] = 0;
    lcur[t] = 0;
    __syncthreads();
    for (int e = bbase + t; e < bend; e += 256) atomicAdd(&ldeg[ebuf[e] >> 17], 1);
    __syncthreads();
    tsum[t] = ldeg[t];
    __syncthreads();
    for (int off = 1; off < 256; off <<= 1) {
        int v = (t >= off) ? tsum[t - off] : 0;
        __syncthreads();
        tsum[t] += v;
        __syncthreads();
    }
    lptr[t] = tsum[t] - ldeg[t];
    __syncthreads();
    int node = cb * 256 + t;
    if (node < N) rowptr[node] = bbase + lptr[t];
    if (cb == 0 && t == 0) rowptr[N] = E;
    for (int e = bbase + t; e < bend; e += 256) {
        unsigned int pk = ebuf[e];
        int dl = pk >> 17;
        int ls = atomicAdd(&lcur[dl], 1);
        adj[bbase + lptr[dl] + ls] = (int)(pk & 0x1FFFF);
    }
}

// ---------------- combined prep: x->fp8 AND weight prep (W0/W1 fp8, W2 bf16) ----------------
__device__ __forceinline__ void prep_w8_body(const float* Wl, const float* Wr,
                                             unsigned char* wf, int t) {
    int total = 8 * 8 * 64 * 8;
    if (t >= total) return;
    int j = t & 7;
    int lane = (t >> 3) & 63;
    int rest = t >> 9;
    int oc = rest % 8;
    int ks = rest / 8;
    int k = ks * 32 + ((lane >> 4) << 3) + j;
    int o = oc * 16 + (lane & 15);
    float v = (k < 128) ? Wl[o * 128 + k] : Wr[o * 128 + (k - 128)];
    wf[t] = f2fp8(v);
}

__device__ __forceinline__ void prep_w2_body(const float* Wl, const float* Wr,
                                             unsigned short* wf, int t) {
    int total = 4 * 8 * 64 * 8;
    if (t >= total) return;
    int j = t & 7;
    int lane = (t >> 3) & 63;
    int rest = t >> 9;
    int oc = rest % 8;
    int ks = rest / 8;
    int k = ks * 32 + ((lane >> 4) << 3) + j;
    int o16 = lane & 15;
    float v = (oc < 4) ? Wl[(oc * 16 + o16) * 128 + k] : Wr[((oc - 4) * 16 + o16) * 128 + k];
    wf[t] = f2bf(v);
}

__global__ __launch_bounds__(256) void k_prep(const float* x, unsigned char* xq, int n4,
                                              const float* Wl0, const float* Wr0, unsigned char* w0,
                                              const float* Wl1, const float* Wr1, unsigned char* w1,
                                              const float* Wl2, const float* Wr2, unsigned short* w2,
                                              int cvtBlocks) {
    int b = blockIdx.x;
    if (b < cvtBlocks) {
        int i = b * 256 + threadIdx.x;
        int idx = i * 4;
        if (idx < n4 * 4) {
            float4 v = *(const float4*)(x + idx);
            *(unsigned int*)(xq + idx) = cvtpk4_fp8(v.x, v.y, v.z, v.w);
        }
    } else if (b < cvtBlocks + 128) {
        prep_w8_body(Wl0, Wr0, w0, (b - cvtBlocks) * 256 + threadIdx.x);
    } else if (b < cvtBlocks + 256) {
        prep_w8_body(Wl1, Wr1, w1, (b - cvtBlocks - 128) * 256 + threadIdx.x);
    } else {
        prep_w2_body(Wl2, Wr2, w2, (b - cvtBlocks - 256) * 256 + threadIdx.x);
    }
}

// ---------------- fp8 mean aggregation -> fp8 mean (32-lane group per node) ----------------
__global__ __launch_bounds__(256) void k_aggr8(const unsigned char* feat, const int* rowptr,
                                               const int* adj, unsigned char* aggr, int N) {
    int g = (blockIdx.x * blockDim.x + threadIdx.x) >> 5;
    int lane = threadIdx.x & 31;
    if (g >= N) return;
    int lo = rowptr[g], hi = rowptr[g + 1];
    float a0 = 0.f, a1 = 0.f, a2 = 0.f, a3 = 0.f;
    const unsigned char* fb = feat + lane * 4;
    int j = lo;
    for (; j + 8 <= hi; j += 8) {
        unsigned int v[8];
#pragma unroll
        for (int u = 0; u < 8; u++) {
            int s = adj[j + u];
            v[u] = *(const unsigned int*)(fb + (size_t)s * 128);
        }
#pragma unroll
        for (int u = 0; u < 8; u++) {
            floatx2 l2 = fp8pk2f<false>(v[u]);
            floatx2 h2 = fp8pk2f<true>(v[u]);
            a0 += l2[0]; a1 += l2[1]; a2 += h2[0]; a3 += h2[1];
        }
    }
    if (j < hi) {  // masked tail chunk: loads issued back-to-back
        unsigned int v[8];
        float w[8];
#pragma unroll
        for (int u = 0; u < 8; u++) {
            int jj = j + u;
            int s = adj[jj < hi ? jj : hi - 1];
            v[u] = *(const unsigned int*)(fb + (size_t)s * 128);
            w[u] = (jj < hi) ? 1.0f : 0.0f;
        }
#pragma unroll
        for (int u = 0; u < 8; u++) {
            floatx2 l2 = fp8pk2f<false>(v[u]);
            floatx2 h2 = fp8pk2f<true>(v[u]);
            a0 = fmaf(w[u], l2[0], a0);
            a1 = fmaf(w[u], l2[1], a1);
            a2 = fmaf(w[u], h2[0], a2);
            a3 = fmaf(w[u], h2[1], a3);
        }
    }
    float inv = 1.0f / (float)max(hi - lo, 1);
    *(unsigned int*)(aggr + (size_t)g * 128 + lane * 4) =
        cvtpk4_fp8(a0 * inv, a1 * inv, a2 * inv, a3 * inv);
}

// ---------------- fused transform, 1-wave blocks (16 rows): fp8 MFMA ----------------
// h = relu([aggr|feat] @ W + b).  STAGE2=false: fp8(h) -> outq.
// STAGE2=true: h stays in LDS; layer-2 (bf16 MFMA): t2 -> t2q (fp8), self -> outf (f32).
template <bool STAGE2>
__global__ __launch_bounds__(64) void k_xform(const unsigned char* aggr,
                                              const unsigned char* featq,
                                              const unsigned char* w8,
                                              const float* bias, unsigned char* outq,
                                              const unsigned short* wf2, const float* bias2,
                                              unsigned char* t2q, float* outf, int N) {
    __shared__ unsigned short st[16][132];
    const int t = threadIdx.x;  // 0..63, single wave
    const int lane = t;
    const int rloc = lane & 15;
    const int bRow0 = blockIdx.x * 16;
    const int row = bRow0 + rloc;
    const int kq = lane >> 4;
    floatx4 acc[8];
#pragma unroll
    for (int i = 0; i < 8; i++) acc[i] = (floatx4)0.0f;
    const bool rowOK = row < N;
    const unsigned char* arow = aggr + (size_t)row * 128;
    const unsigned char* frow = featq + (size_t)row * 128;
    const long* bbase = (const long*)w8;
#pragma unroll
    for (int ks = 0; ks < 8; ks++) {
        long a;
        if (!rowOK) {
            a = 0;
        } else {
            const unsigned char* p =
                (ks < 4) ? (arow + ks * 32 + kq * 8) : (frow + (ks - 4) * 32 + kq * 8);
            a = *(const long*)p;
        }
#pragma unroll
        for (int oc = 0; oc < 8; oc++) {
            acc[oc] = __builtin_amdgcn_mfma_f32_16x16x32_fp8_fp8(
                a, bbase[(ks * 8 + oc) * 64 + lane], acc[oc], 0, 0, 0);
        }
    }
    const int rl = kq * 4;
#pragma unroll
    for (int oc = 0; oc < 8; oc++) {
        int o = oc * 16 + (lane & 15);
        float bv = bias[o];
#pragma unroll
        for (int j = 0; j < 4; j++) {
            float v = fmaxf(acc[oc][j] + bv, 0.0f);
            st[rl + j][o] = f2bf(v);
        }
    }
    __syncthreads();
    if (!STAGE2) {
        // coalesced fp8 h stores: 128 chunks of 16 B, 2 per lane
#pragma unroll
        for (int i = 0; i < 2; i++) {
            int c = t + i * 64;
            int r = c >> 3;
            int pos = (c & 7) * 16;
            int node = bRow0 + r;
            if (node < N) {
                short8 v0 = *(const short8*)&st[r][pos];
                short8 v1 = *(const short8*)&st[r][pos + 8];
                *(uint4*)(outq + (size_t)node * 128 + pos) = pack16_fp8(v0, v1);
            }
        }
    } else {
        // ---- stage 2: layer-2 transform from LDS h-tile (bf16 MFMA, bf16 W2) ----
        floatx4 acc2[8];
#pragma unroll
        for (int i = 0; i < 8; i++) acc2[i] = (floatx4)0.0f;
        const short8* bbase2 = (const short8*)wf2;
#pragma unroll
        for (int ks = 0; ks < 4; ks++) {
            short8 a = *(const short8*)&st[rloc][ks * 32 + kq * 8];
#pragma unroll
            for (int oc = 0; oc < 8; oc++) {
                short8 b = bbase2[(ks * 8 + oc) * 64 + lane];
                acc2[oc] = __builtin_amdgcn_mfma_f32_16x16x32_bf16(a, b, acc2[oc], 0, 0, 0);
            }
        }
        __syncthreads();  // done reading h from st; safe to overwrite
        const int o16 = lane & 15;
#pragma unroll
        for (int oc = 0; oc < 8; oc++) {
#pragma unroll
            for (int j = 0; j < 4; j++) {
                int node = bRow0 + kq * 4 + j;
                if (oc < 4) {
                    st[rl + j][oc * 16 + o16] = f2bf(acc2[oc][j]);  // t2 tile (cols 0..63)
                } else if (node < N) {
                    int o = (oc - 4) * 16 + o16;
                    outf[(size_t)node * 64 + o] = acc2[oc][j] + bias2[o];  // self (full-line)
                }
            }
        }
        __syncthreads();
        // coalesced fp8 t2 stores: 64 chunks of 16 B (16 rows x 64 B), 1 per lane
        {
            int r = t >> 2;
            int pos = (t & 3) * 16;
            int node = bRow0 + r;
            if (node < N) {
                short8 v0 = *(const short8*)&st[r][pos];
                short8 v1 = *(const short8*)&st[r][pos + 8];
                *(uint4*)(t2q + (size_t)node * 64 + pos) = pack16_fp8(v0, v1);
            }
        }
    }
}

// 64-wide fp8 mean aggregation of t2 + add self + fused log_softmax (16-lane group/node)
__global__ __launch_bounds__(256) void k_aggr64lsm(const unsigned char* t2q, const int* rowptr,
                                                   const int* adj, float* out, int N) {
    int g = (blockIdx.x * blockDim.x + threadIdx.x) >> 4;
    int lane = threadIdx.x & 15;
    if (g >= N) return;
    int lo = rowptr[g], hi = rowptr[g + 1];
    float a0 = 0.f, a1 = 0.f, a2 = 0.f, a3 = 0.f;
    const unsigned char* fb = t2q + lane * 4;
    int j = lo;
    for (; j + 8 <= hi; j += 8) {
        unsigned int v[8];
#pragma unroll
        for (int u = 0; u < 8; u++) {
            int s = adj[j + u];
            v[u] = *(const unsigned int*)(fb + (size_t)s * 64);
        }
#pragma unroll
        for (int u = 0; u < 8; u++) {
            floatx2 l2 = fp8pk2f<false>(v[u]);
            floatx2 h2 = fp8pk2f<true>(v[u]);
            a0 += l2[0]; a1 += l2[1]; a2 += h2[0]; a3 += h2[1];
        }
    }
    if (j < hi) {
        unsigned int v[8];
        float w[8];
#pragma unroll
        for (int u = 0; u < 8; u++) {
            int jj = j + u;
            int s = adj[jj < hi ? jj : hi - 1];
            v[u] = *(const unsigned int*)(fb + (size_t)s * 64);
            w[u] = (jj < hi) ? 1.0f : 0.0f;
        }
#pragma unroll
        for (int u = 0; u < 8; u++) {
            floatx2 l2 = fp8pk2f<false>(v[u]);
            floatx2 h2 = fp8pk2f<true>(v[u]);
            a0 = fmaf(w[u], l2[0], a0);
            a1 = fmaf(w[u], l2[1], a1);
            a2 = fmaf(w[u], h2[0], a2);
            a3 = fmaf(w[u], h2[1], a3);
        }
    }
    float inv = 1.0f / (float)max(hi - lo, 1);
    float* op = out + (size_t)g * 64 + lane * 4;
    float4 cur = *(float4*)op;
    float v0 = cur.x + a0 * inv, v1 = cur.y + a1 * inv;
    float v2 = cur.z + a2 * inv, v3 = cur.w + a3 * inv;
    float m = fmaxf(fmaxf(v0, v1), fmaxf(v2, v3));
#pragma unroll
    for (int off = 8; off; off >>= 1) m = fmaxf(m, __shfl_xor(m, off));
    float s = expf(v0 - m) + expf(v1 - m) + expf(v2 - m) + expf(v3 - m);
#pragma unroll
    for (int off = 8; off; off >>= 1) s += __shfl_xor(s, off);
    float ls = m + logf(s);
    float4 o;
    o.x = v0 - ls; o.y = v1 - ls; o.z = v2 - ls; o.w = v3 - ls;
    *(float4*)op = o;
}

extern "C" void kernel_launch(void* const* d_in, const int* in_sizes, int n_in,
                              void* d_out, int out_size, void* d_ws, size_t ws_size,
                              hipStream_t stream) {
    const float* x = (const float*)d_in[0];
    const int* ei = (const int*)d_in[1];
    const float* Wl0 = (const float*)d_in[2];
    const float* bl0 = (const float*)d_in[3];
    const float* Wr0 = (const float*)d_in[4];
    const float* Wl1 = (const float*)d_in[5];
    const float* bl1 = (const float*)d_in[6];
    const float* Wr1 = (const float*)d_in[7];
    const float* Wl2 = (const float*)d_in[8];
    const float* bl2 = (const float*)d_in[9];
    const float* Wr2 = (const float*)d_in[10];

    const int N = in_sizes[0] / 128;
    const int E = in_sizes[1] / 2;
    const int* src = ei;
    const int* dst = ei + E;

    char* ws = (char*)d_ws;
    size_t off = 0;
    auto alloc = [&](size_t bytes) {
        void* p = ws + off;
        off += (bytes + 255) & ~(size_t)255;
        return p;
    };
    int* cntin = (int*)alloc((size_t)NB * B1 * 4);
    int* cntoff = (int*)alloc(((size_t)NB * B1 + 1) * 4);
    int* bsum = (int*)alloc(1024 * 4);
    unsigned int* ebuf = (unsigned int*)alloc((size_t)E * 4);
    int* rowptr = (int*)alloc((size_t)(N + 1) * 4);
    int* adj = (int*)alloc((size_t)E * 4);
    unsigned char* abuf = (unsigned char*)alloc((size_t)N * 128);  // fp8 aggr; reused as fp8 t2
    unsigned char* q8a = (unsigned char*)alloc((size_t)N * 128);   // fp8(x)
    unsigned char* q8b = (unsigned char*)alloc((size_t)N * 128);   // fp8(h0)
    unsigned char* w0 = (unsigned char*)alloc(8 * 8 * 64 * 8);     // fp8 weights L0 (32 KB)
    unsigned char* w1 = (unsigned char*)alloc(8 * 8 * 64 * 8);     // fp8 weights L1 (32 KB)
    unsigned short* w2 = (unsigned short*)alloc(4 * 8 * 64 * 8 * 2);  // bf16 weights L2

    // ---- bucketed CSR build ----
    const int NBUCK = (N + 255) >> 8;
    k_bhist<<<B1, 256, 0, stream>>>(dst, E, cntin);
    const int scanLen = NB * B1;
    const int nScanBlocks = (scanLen + SCAN_CHUNK - 1) / SCAN_CHUNK;
    k_scan_part<<<nScanBlocks, SCAN_T, 0, stream>>>(cntin, bsum, scanLen);
    k_scan_top<<<1, 64, 0, stream>>>(bsum, nScanBlocks);
    k_scan_apply<<<nScanBlocks, SCAN_T, 0, stream>>>(cntin, bsum, cntoff, scanLen);
    k_bscatter<<<B1, 256, 0, stream>>>(src, dst, E, cntoff, ebuf);
    k_build<<<NBUCK, 256, 0, stream>>>(ebuf, cntoff, rowptr, adj, N, E);

    // combined conversion + weight prep (one launch)
    const int cvtBlocks = ((N * 128 / 4) + 255) / 256;
    k_prep<<<cvtBlocks + 128 + 128 + 64, 256, 0, stream>>>(
        x, q8a, N * 128 / 4, Wl0, Wr0, w0, Wl1, Wr1, w1, Wl2, Wr2, w2, cvtBlocks);

    const int aggrGrid = ((N * 32) + 255) / 256;
    const int aggr64Grid = ((N * 16) + 255) / 256;
    const int xfGrid = (N + 15) / 16;  // 1-wave blocks, 16 rows each

    unsigned char* aggr = abuf;
    unsigned char* t2q = abuf;

    // layer 0: gather fp8(x) -> fp8 mean; xform([aggr|x]) -> fp8(h0)
    k_aggr8<<<aggrGrid, 256, 0, stream>>>(q8a, rowptr, adj, aggr, N);
    k_xform<false><<<xfGrid, 64, 0, stream>>>(aggr, q8a, w0, bl0, q8b,
                                              nullptr, nullptr, nullptr, nullptr, N);
    // layer 1: gather fp8(h0) -> fp8 mean; xform([aggr|h0]) -> h1 (LDS only)
    //          + fused layer-2 transform: t2q (fp8) + self (f32 -> d_out)
    k_aggr8<<<aggrGrid, 256, 0, stream>>>(q8b, rowptr, adj, aggr, N);
    k_xform<true><<<xfGrid, 64, 0, stream>>>(aggr, q8b, w1, bl1, nullptr,
                                             w2, bl2, t2q, (float*)d_out, N);
    // layer 2 aggregation: fused fp8 aggregate + log_softmax
    k_aggr64lsm<<<aggr64Grid, 256, 0, stream>>>(t2q, rowptr, adj, (float*)d_out, N);
}